// Round 7
// baseline (249.809 us; speedup 1.0000x reference)
//
#include <hip/hip_runtime.h>
#include <hip/hip_bf16.h>

#define BATCH 16
#define T 256
#define DHW 5760  // 3*30*64
#define NWG 8     // GRU workgroups; WG i owns h-columns [32i, 32i+32)

typedef __bf16 bf16x8 __attribute__((ext_vector_type(8)));
typedef __bf16 bf16x4 __attribute__((ext_vector_type(4)));
typedef float f32x4 __attribute__((ext_vector_type(4)));

// ---------- gate nonlinearities: odd Taylor, |arg| <~ 0.5 ----------
// sigm with PRE-HALVED argument u = x/2 (weights+gi for r,z are pre-scaled 0.5)
__device__ __forceinline__ float sigm_h(float u) {
    float t = u * u;
    float q = fmaf(t, fmaf(t, 1.0f / 15.0f, -1.0f / 6.0f), 0.5f);
    return fmaf(u, q, 0.5f);
}
__device__ __forceinline__ float tanh7(float x) {
    float t = x * x;
    float p = fmaf(t, fmaf(t, fmaf(t, -17.0f / 315.0f, 2.0f / 15.0f), -1.0f / 3.0f), 1.0f);
    return x * p;
}

// ---------- kernel W: w_hh f32 -> bf16, row-major [768][256] ----------
__global__ void wcvt_kernel(const float* __restrict__ w_hh, __bf16* __restrict__ wbf) {
    const int idx = blockIdx.x * 256 + threadIdx.x;
    const float s = (idx < 32768) ? 0.5f : 1.0f;  // rows<512 (r,z) pre-halved
    const float4 v = ((const float4*)w_hh)[idx];
    bf16x4 o;
    o[0] = (__bf16)(v.x * s); o[1] = (__bf16)(v.y * s);
    o[2] = (__bf16)(v.z * s); o[3] = (__bf16)(v.w * s);
    *(bf16x4*)(wbf + (size_t)idx * 4) = o;
}

// ---------- kernel A: global average pool ----------
__global__ void pool_kernel(const float* __restrict__ x, float* __restrict__ g) {
    const int row = blockIdx.x;
    const float4* xr = (const float4*)(x + (size_t)row * DHW);
    float s = 0.0f;
    for (int i = threadIdx.x; i < DHW / 4; i += 256) {
        float4 v = xr[i];
        s += (v.x + v.y) + (v.z + v.w);
    }
    #pragma unroll
    for (int off = 32; off > 0; off >>= 1) s += __shfl_down(s, off, 64);
    __shared__ float red[4];
    const int lane = threadIdx.x & 63, wv = threadIdx.x >> 6;
    if (lane == 0) red[wv] = s;
    __syncthreads();
    if (threadIdx.x == 0) {
        float t = (red[0] + red[1]) + (red[2] + red[3]);
        g[row] = t * (1.0f / (float)DHW);
    }
}

// ---------- kernel B1 ----------
__global__ void mask_kernel(const float* __restrict__ g, const float* __restrict__ conv_w,
                            const float* __restrict__ conv_b, float* __restrict__ mask) {
    const int o = blockIdx.x, i = threadIdx.x;
    const int lane = i & 63, wv = i >> 6;
    const float wt = conv_w[o * 768 + 3 * i + 1];
    __shared__ float part[16][4];
    #pragma unroll 4
    for (int b = 0; b < 16; ++b) {
        float v = wt * g[b * 256 + i];
        #pragma unroll
        for (int off = 32; off > 0; off >>= 1) v += __shfl_down(v, off, 64);
        if (lane == 0) part[b][wv] = v;
    }
    __syncthreads();
    if (i < 16)
        mask[i * 256 + o] = part[i][0] + part[i][1] + part[i][2] + part[i][3] + conv_b[o];
}

// ---------- kernel B2 ----------
__global__ void gi_kernel(const float* __restrict__ mask, const float* __restrict__ w_ih,
                          const float* __restrict__ b_ih, float* __restrict__ gi) {
    const int j = blockIdx.x, o = threadIdx.x;
    const int lane = o & 63, wv = o >> 6;
    const float wt = w_ih[j * 256 + o];
    __shared__ float part[16][4];
    #pragma unroll 4
    for (int b = 0; b < 16; ++b) {
        float v = wt * mask[b * 256 + o];
        #pragma unroll
        for (int off = 32; off > 0; off >>= 1) v += __shfl_down(v, off, 64);
        if (lane == 0) part[b][wv] = v;
    }
    __syncthreads();
    if (o < 16) gi[o * 768 + j] = part[o][0] + part[o][1] + part[o][2] + part[o][3] + b_ih[j];
}

// ---------- prelude: zero barrier counter + per-step change flags ----------
__global__ void barinit_kernel(int* __restrict__ bar, int* __restrict__ chg) {
    if (threadIdx.x == 0) *bar = 0;
    chg[threadIdx.x] = 0;  // 256 slots
}

// ---------- kernel C: distributed GRU, 8 WGs x 256 thr ----------
// ROUND-7: round 6 proved the distributed structure (gru 131 -> ~55 us). This
// round removes per-step overhead from the serial chain while keeping the
// PROVEN arrival protocol (publish -> drain-sync -> tid0 release-add ->
// acquire spin) unchanged:
//  (a) A-fragments load DIRECTLY from the hg exchange buffer into registers
//      (addresses match the MFMA A layout) -- kills the gather->LDS->ds_read
//      round-trip, the hb buffer, its zero-init, and one __syncthreads.
//  (b) exit flag read DEFERRED: chg[t-1] is final once bar >= 8t (each WG's
//      or precedes its release-add), so tid0 reads it right after the spin --
//      kills the sflag broadcast + extra barrier inside the arrival.
// Buffer-reuse safety (2 buffers): a WG reaches step t+2's publish of
// hg[t&1] only after its spin saw bar >= 8(t+1), which certifies every WG
// finished step t+1 -- whose MFMA consumed hg[t&1]. No WG can lead by 2.
__global__ __launch_bounds__(256) void gru_kernel(
    const float* __restrict__ gi,    // [16][768]
    const __bf16* __restrict__ wbf,  // [768][256] bf16 (rows<512 pre-halved)
    const float* __restrict__ b_hh,  // [768]
    float* __restrict__ out,         // [16][256][256]
    int* __restrict__ meta,          // [0] = S
    int* __restrict__ bar,           // monotonic arrival counter
    int* __restrict__ chg,           // [256] per-step change flags
    unsigned* __restrict__ hg0,      // h exchange buf A: [16][128] u32
    unsigned* __restrict__ hg1)      // h exchange buf B
{
    __shared__ __align__(16) float X[6 * 256 * 4];   // 24576 B gate exchange
    __shared__ __align__(16) float CI0[768], CI1[768];  // gate-wave C-inits
    __shared__ float gnl[16][33];                    // gi_n slice
    __shared__ int sexit;

    const int tid = threadIdx.x;
    const int w = tid >> 6;          // wave 0..3 (0-2 compute gates r,z,n)
    const int lane = tid & 63;
    const int l15 = lane & 15;
    const int quad = lane >> 4;
    const int wg = blockIdx.x;
    const int cb = wg * 32;          // column base of this WG

    // ---- B-frags: wave w<3 owns gate w, col-tiles 0/1 -> 64 regs/wave ----
    bf16x8 B0[8], B1[8];
    if (w < 3) {
        const __bf16* wr0 = wbf + (size_t)(w * 256 + cb + l15) * 256 + quad * 8;
        const __bf16* wr1 = wr0 + 16 * 256;
        #pragma unroll
        for (int kc = 0; kc < 8; ++kc) {
            B0[kc] = *(const bf16x8*)(wr0 + kc * 32);
            B1[kc] = *(const bf16x8*)(wr1 + kc * 32);
            asm volatile("" : "+v"(B0[kc]), "+v"(B1[kc]));
        }
        // C-inits to LDS (register relief; re-read each step, 2 ds_read_b128)
        const int widx = w * 64 + lane;
        f32x4 c0, c1;
        if (w == 2) {  // n-gate C-init = b_hh_n broadcast (gi_n added in epilogue)
            const float bn0 = b_hh[512 + cb + l15];
            const float bn1 = b_hh[512 + cb + 16 + l15];
            c0[0] = bn0; c0[1] = bn0; c0[2] = bn0; c0[3] = bn0;
            c1[0] = bn1; c1[1] = bn1; c1[2] = bn1; c1[3] = bn1;
        } else {       // r/z C-init = 0.5*(gi + b_hh), rows = quad*4+i
            const int o0 = w * 256 + cb + l15;
            #pragma unroll
            for (int i = 0; i < 4; ++i) {
                c0[i] = (gi[(size_t)(quad * 4 + i) * 768 + o0] + b_hh[o0]) * 0.5f;
                c1[i] = (gi[(size_t)(quad * 4 + i) * 768 + o0 + 16] + b_hh[o0 + 16]) * 0.5f;
            }
        }
        *(f32x4*)&CI0[widx * 4] = c0;
        *(f32x4*)&CI1[widx * 4] = c1;
    }
    for (int e = tid; e < 512; e += 256)
        gnl[e >> 5][e & 31] = gi[(size_t)(e >> 5) * 768 + 512 + cb + (e & 31)];

    const int erow = tid >> 4;        // epilogue: batch row 0..15
    const int ec = (tid & 15) * 2;    // epilogue: local col pair
    float hp0 = 0.0f, hp1 = 0.0f;     // previous h for this thread's 2 elements
    int S = 255;
    __syncthreads();

    for (int t = 0; t < 256; ++t) {
        // ---- MFMA phase (gate waves): spin, direct-reg A loads, 16 MFMA ----
        if (w < 3) {
            const int widx = w * 64 + lane;
            f32x4 a0 = *(const f32x4*)&CI0[widx * 4];
            f32x4 a1 = *(const f32x4*)&CI1[widx * 4];
            if (t > 0) {
                while (__hip_atomic_load(bar, __ATOMIC_ACQUIRE,
                                         __HIP_MEMORY_SCOPE_AGENT) < NWG * t)
                    __builtin_amdgcn_s_sleep(1);
                // deferred exit flag: chg[t-1] is final once bar >= 8t
                if (tid == 0)
                    sexit = __hip_atomic_load(&chg[t - 1], __ATOMIC_RELAXED,
                                              __HIP_MEMORY_SCOPE_AGENT);
                const unsigned* hgr = ((t - 1) & 1) ? hg1 : hg0;
                const unsigned* pb = hgr + l15 * 128 + quad * 4;
                bf16x8 av[8];
                #pragma unroll
                for (int kc = 0; kc < 8; ++kc) {  // 32 loads, all in flight
                    uint4 u;
                    u.x = __hip_atomic_load(pb + kc * 16 + 0, __ATOMIC_RELAXED, __HIP_MEMORY_SCOPE_AGENT);
                    u.y = __hip_atomic_load(pb + kc * 16 + 1, __ATOMIC_RELAXED, __HIP_MEMORY_SCOPE_AGENT);
                    u.z = __hip_atomic_load(pb + kc * 16 + 2, __ATOMIC_RELAXED, __HIP_MEMORY_SCOPE_AGENT);
                    u.w = __hip_atomic_load(pb + kc * 16 + 3, __ATOMIC_RELAXED, __HIP_MEMORY_SCOPE_AGENT);
                    av[kc] = __builtin_bit_cast(bf16x8, u);
                }
                #pragma unroll
                for (int kc = 0; kc < 8; ++kc) {
                    a0 = __builtin_amdgcn_mfma_f32_16x16x32_bf16(av[kc], B0[kc], a0, 0, 0, 0);
                    a1 = __builtin_amdgcn_mfma_f32_16x16x32_bf16(av[kc], B1[kc], a1, 0, 0, 0);
                }
            }
            *(f32x4*)&X[((w * 2 + 0) * 256 + lane) * 4] = a0;
            *(f32x4*)&X[((w * 2 + 1) * 256 + lane) * 4] = a1;
        }
        __syncthreads();                                // S1: X ready
        if (t > 0 && sexit == 0) { S = t - 1; break; }  // unanimous (final chg value)

        // ---- epilogue: combine gates for elements (erow, ec) and (erow, ec+1) ----
        float hv0, hv1;
        bool mv = false;
        {
            const int c0 = ec, c1 = ec + 1;
            const int xb0 = ((c0 >> 4) * 256 + (erow >> 2) * 16 + (c0 & 15)) * 4 + (erow & 3);
            float r = sigm_h(X[xb0]);
            float z = sigm_h(X[xb0 + 2048]);
            float n = tanh7(fmaf(r, X[xb0 + 4096], gnl[erow][c0]));
            hv0 = fmaf(z, hp0 - n, n);
            mv |= fabsf(hv0 - hp0) > 1e-4f;
            hp0 = hv0;
            const int xb1 = ((c1 >> 4) * 256 + (erow >> 2) * 16 + (c1 & 15)) * 4 + (erow & 3);
            r = sigm_h(X[xb1]);
            z = sigm_h(X[xb1 + 2048]);
            n = tanh7(fmaf(r, X[xb1 + 4096], gnl[erow][c1]));
            hv1 = fmaf(z, hp1 - n, n);
            mv |= fabsf(hv1 - hp1) > 1e-4f;
            hp1 = hv1;
        }
        // out row t (f32, full precision)
        *(float2*)&out[(size_t)erow * 65536 + (size_t)t * 256 + cb + ec] = make_float2(hv0, hv1);
        // publish h slice as bf16 pair -> agent-visible
        {
            unsigned p = ((unsigned)__builtin_bit_cast(unsigned short, (__bf16)hv1) << 16)
                       |  (unsigned)__builtin_bit_cast(unsigned short, (__bf16)hv0);
            unsigned* hgw = (t & 1) ? hg1 : hg0;
            __hip_atomic_store(&hgw[erow * 128 + (cb + ec) / 2], p,
                               __ATOMIC_RELAXED, __HIP_MEMORY_SCOPE_AGENT);
        }
        const bool wmv = __any(mv);
        __syncthreads();      // S2: drain all waves' stores (vmcnt0) + X protect
        if (lane == 0 && wmv)
            __hip_atomic_fetch_or(&chg[t], 1, __ATOMIC_RELAXED, __HIP_MEMORY_SCOPE_AGENT);
        if (tid == 0)
            __hip_atomic_fetch_add(bar, 1, __ATOMIC_RELEASE, __HIP_MEMORY_SCOPE_AGENT);
    }

    if (wg == 0 && tid == 0) meta[0] = S;
}

// ---------- kernel D: replicate row S into rows S+1..255 ----------
__global__ void fill_kernel(const int* __restrict__ meta, float* __restrict__ out) {
    const int S = meta[0];
    const int r = S + 1 + blockIdx.x;
    if (r > 255) return;
    const int c = threadIdx.x;
    #pragma unroll 4
    for (int b = 0; b < 16; ++b)
        out[b * 65536 + r * 256 + c] = out[b * 65536 + S * 256 + c];
}

extern "C" void kernel_launch(void* const* d_in, const int* in_sizes, int n_in,
                              void* d_out, int out_size, void* d_ws, size_t ws_size,
                              hipStream_t stream) {
    const float* x      = (const float*)d_in[0];
    const float* conv_w = (const float*)d_in[1];
    const float* conv_b = (const float*)d_in[2];
    const float* w_ih   = (const float*)d_in[3];
    const float* w_hh   = (const float*)d_in[4];
    const float* b_ih   = (const float*)d_in[5];
    const float* b_hh   = (const float*)d_in[6];
    float* out = (float*)d_out;

    float* ws    = (float*)d_ws;
    float* g     = ws;                         // 4096 floats
    float* maskb = ws + 4096;                  // 4096
    float* gib   = ws + 8192;                  // 12288
    int*   meta  = (int*)(ws + 20480);         // 1 int
    int*   bar   = (int*)(ws + 20512);         // own cacheline
    int*   chg   = (int*)(ws + 20544);         // 256 ints
    __bf16* wbf  = (__bf16*)(ws + 20816);      // 196608 bf16 (384 KB), 16B-aligned
    unsigned* hg0 = (unsigned*)(ws + 119120);  // 2048 u32 (8 KB)
    unsigned* hg1 = (unsigned*)(ws + 121168);  // 2048 u32

    barinit_kernel<<<1, 256, 0, stream>>>(bar, chg);
    wcvt_kernel<<<192, 256, 0, stream>>>(w_hh, wbf);
    pool_kernel<<<BATCH * T, 256, 0, stream>>>(x, g);
    mask_kernel<<<T, 256, 0, stream>>>(g, conv_w, conv_b, maskb);
    gi_kernel<<<3 * T, 256, 0, stream>>>(maskb, w_ih, b_ih, gib);
    gru_kernel<<<NWG, 256, 0, stream>>>(gib, wbf, b_hh, out, meta, bar, chg, hg0, hg1);
    fill_kernel<<<T - 1, 256, 0, stream>>>(meta, out);
}

// Round 8
// 221.839 us; speedup vs baseline: 1.1261x; 1.1261x over previous
//
#include <hip/hip_runtime.h>
#include <hip/hip_bf16.h>

#define BATCH 16
#define T 256
#define DHW 5760  // 3*30*64
#define NWG 8     // GRU workgroups; WG i owns h-columns [32i, 32i+32) = K-chunk i

typedef __bf16 bf16x8 __attribute__((ext_vector_type(8)));
typedef __bf16 bf16x4 __attribute__((ext_vector_type(4)));
typedef float f32x4 __attribute__((ext_vector_type(4)));

// ---------- gate nonlinearities: odd Taylor, |arg| <~ 0.5 ----------
// sigm with PRE-HALVED argument u = x/2 (weights+gi for r,z are pre-scaled 0.5)
__device__ __forceinline__ float sigm_h(float u) {
    float t = u * u;
    float q = fmaf(t, fmaf(t, 1.0f / 15.0f, -1.0f / 6.0f), 0.5f);
    return fmaf(u, q, 0.5f);
}
__device__ __forceinline__ float tanh7(float x) {
    float t = x * x;
    float p = fmaf(t, fmaf(t, fmaf(t, -17.0f / 315.0f, 2.0f / 15.0f), -1.0f / 3.0f), 1.0f);
    return x * p;
}

// Cross-XCD coherent 16-B load: sc0 sc1 bypasses L1 + per-XCD L2 (reads the
// IF coherence point) -- same semantics as agent-scope atomic loads, but
// vectorized. Result regs are NOT valid until the vmcnt fence below.
__device__ __forceinline__ uint4 ldg_coherent(const uint4* p) {
    uint4 r;
    asm volatile("global_load_dwordx4 %0, %1, off sc0 sc1" : "=v"(r) : "v"(p));
    return r;
}

// ---------- kernel W: w_hh f32 -> bf16, row-major [768][256] ----------
__global__ void wcvt_kernel(const float* __restrict__ w_hh, __bf16* __restrict__ wbf) {
    const int idx = blockIdx.x * 256 + threadIdx.x;
    const float s = (idx < 32768) ? 0.5f : 1.0f;  // rows<512 (r,z) pre-halved
    const float4 v = ((const float4*)w_hh)[idx];
    bf16x4 o;
    o[0] = (__bf16)(v.x * s); o[1] = (__bf16)(v.y * s);
    o[2] = (__bf16)(v.z * s); o[3] = (__bf16)(v.w * s);
    *(bf16x4*)(wbf + (size_t)idx * 4) = o;
}

// ---------- kernel A: global average pool ----------
__global__ void pool_kernel(const float* __restrict__ x, float* __restrict__ g) {
    const int row = blockIdx.x;
    const float4* xr = (const float4*)(x + (size_t)row * DHW);
    float s = 0.0f;
    for (int i = threadIdx.x; i < DHW / 4; i += 256) {
        float4 v = xr[i];
        s += (v.x + v.y) + (v.z + v.w);
    }
    #pragma unroll
    for (int off = 32; off > 0; off >>= 1) s += __shfl_down(s, off, 64);
    __shared__ float red[4];
    const int lane = threadIdx.x & 63, wv = threadIdx.x >> 6;
    if (lane == 0) red[wv] = s;
    __syncthreads();
    if (threadIdx.x == 0) {
        float t = (red[0] + red[1]) + (red[2] + red[3]);
        g[row] = t * (1.0f / (float)DHW);
    }
}

// ---------- kernel B1 ----------
__global__ void mask_kernel(const float* __restrict__ g, const float* __restrict__ conv_w,
                            const float* __restrict__ conv_b, float* __restrict__ mask) {
    const int o = blockIdx.x, i = threadIdx.x;
    const int lane = i & 63, wv = i >> 6;
    const float wt = conv_w[o * 768 + 3 * i + 1];
    __shared__ float part[16][4];
    #pragma unroll 4
    for (int b = 0; b < 16; ++b) {
        float v = wt * g[b * 256 + i];
        #pragma unroll
        for (int off = 32; off > 0; off >>= 1) v += __shfl_down(v, off, 64);
        if (lane == 0) part[b][wv] = v;
    }
    __syncthreads();
    if (i < 16)
        mask[i * 256 + o] = part[i][0] + part[i][1] + part[i][2] + part[i][3] + conv_b[o];
}

// ---------- kernel B2 ----------
__global__ void gi_kernel(const float* __restrict__ mask, const float* __restrict__ w_ih,
                          const float* __restrict__ b_ih, float* __restrict__ gi) {
    const int j = blockIdx.x, o = threadIdx.x;
    const int lane = o & 63, wv = o >> 6;
    const float wt = w_ih[j * 256 + o];
    __shared__ float part[16][4];
    #pragma unroll 4
    for (int b = 0; b < 16; ++b) {
        float v = wt * mask[b * 256 + o];
        #pragma unroll
        for (int off = 32; off > 0; off >>= 1) v += __shfl_down(v, off, 64);
        if (lane == 0) part[b][wv] = v;
    }
    __syncthreads();
    if (o < 16) gi[o * 768 + j] = part[o][0] + part[o][1] + part[o][2] + part[o][3] + b_ih[j];
}

// ---------- prelude: zero barrier counter + per-step change flags ----------
__global__ void barinit_kernel(int* __restrict__ bar, int* __restrict__ chg) {
    if (threadIdx.x == 0) *bar = 0;
    chg[threadIdx.x] = 0;  // 256 slots
}

// ---------- kernel C: distributed GRU, 8 WGs x 256 thr ----------
// ROUND-8: round 7's regression (77us, FETCH 727KB) was the A-load leg: 32
// SCALAR u32 atomic loads/lane at 512-B row stride = 6%-dense scatters. Fix:
// CHUNK-TILED exchange layout. WG wg's 32 columns are exactly K-chunk wg, so
// it publishes its h slice CONTIGUOUSLY at u32 [wg*256 + tid] (coalesced 1 KB
// store). Consumer's A-frag for chunk kc = uint4 at [kc*64 + l15*4 + quad]:
// 8 dense vector loads per wave, issued sc0+sc1 (IF-coherent, cross-XCD safe)
// with an explicit vmcnt(0)+sched_barrier fence before the MFMAs.
// Race fix vs r7: chg-OR now done by tid0 BEFORE its release-add (ordered),
// with per-wave flags passed through LDS pre-S2.
// Buffer-reuse safety (2 buffers): a WG publishes hg[t&1] at step t only
// after its spin saw bar >= 8t, certifying all WGs consumed hg[t&1] at step
// t-1 (their loads complete before their arrive). No WG can lead by 2.
__global__ __launch_bounds__(256) void gru_kernel(
    const float* __restrict__ gi,    // [16][768]
    const __bf16* __restrict__ wbf,  // [768][256] bf16 (rows<512 pre-halved)
    const float* __restrict__ b_hh,  // [768]
    float* __restrict__ out,         // [16][256][256]
    int* __restrict__ meta,          // [0] = S
    int* __restrict__ bar,           // monotonic arrival counter
    int* __restrict__ chg,           // [256] per-step change flags
    unsigned* __restrict__ hg0,      // h exchange buf A: chunk-tiled [8][16][16] u32
    unsigned* __restrict__ hg1)      // h exchange buf B
{
    __shared__ __align__(16) float X[6 * 256 * 4];      // 24576 B gate exchange
    __shared__ __align__(16) float CI0[768], CI1[768];  // gate-wave C-inits
    __shared__ float gnl[16][33];                       // gi_n slice
    __shared__ int wchg[4];
    __shared__ int sexit;

    const int tid = threadIdx.x;
    const int w = tid >> 6;          // wave 0..3 (0-2 compute gates r,z,n)
    const int lane = tid & 63;
    const int l15 = lane & 15;
    const int quad = lane >> 4;
    const int wg = blockIdx.x;
    const int cb = wg * 32;          // column base of this WG

    // ---- B-frags: wave w<3 owns gate w, col-tiles 0/1 -> 64 regs/wave ----
    bf16x8 B0[8], B1[8];
    if (w < 3) {
        const __bf16* wr0 = wbf + (size_t)(w * 256 + cb + l15) * 256 + quad * 8;
        const __bf16* wr1 = wr0 + 16 * 256;
        #pragma unroll
        for (int kc = 0; kc < 8; ++kc) {
            B0[kc] = *(const bf16x8*)(wr0 + kc * 32);
            B1[kc] = *(const bf16x8*)(wr1 + kc * 32);
            asm volatile("" : "+v"(B0[kc]), "+v"(B1[kc]));
        }
        // C-inits to LDS (register relief; re-read each step, 2 ds_read_b128)
        const int widx = w * 64 + lane;
        f32x4 c0, c1;
        if (w == 2) {  // n-gate C-init = b_hh_n broadcast (gi_n added in epilogue)
            const float bn0 = b_hh[512 + cb + l15];
            const float bn1 = b_hh[512 + cb + 16 + l15];
            c0[0] = bn0; c0[1] = bn0; c0[2] = bn0; c0[3] = bn0;
            c1[0] = bn1; c1[1] = bn1; c1[2] = bn1; c1[3] = bn1;
        } else {       // r/z C-init = 0.5*(gi + b_hh), rows = quad*4+i
            const int o0 = w * 256 + cb + l15;
            #pragma unroll
            for (int i = 0; i < 4; ++i) {
                c0[i] = (gi[(size_t)(quad * 4 + i) * 768 + o0] + b_hh[o0]) * 0.5f;
                c1[i] = (gi[(size_t)(quad * 4 + i) * 768 + o0 + 16] + b_hh[o0 + 16]) * 0.5f;
            }
        }
        *(f32x4*)&CI0[widx * 4] = c0;
        *(f32x4*)&CI1[widx * 4] = c1;
    }
    for (int e = tid; e < 512; e += 256)
        gnl[e >> 5][e & 31] = gi[(size_t)(e >> 5) * 768 + 512 + cb + (e & 31)];

    const int erow = tid >> 4;        // epilogue: batch row 0..15
    const int ec = (tid & 15) * 2;    // epilogue: local col pair
    float hp0 = 0.0f, hp1 = 0.0f;     // previous h for this thread's 2 elements
    int S = 255;
    __syncthreads();

    for (int t = 0; t < 256; ++t) {
        // ---- MFMA phase (gate waves): spin, tiled vector A loads, 16 MFMA ----
        if (w < 3) {
            const int widx = w * 64 + lane;
            f32x4 a0 = *(const f32x4*)&CI0[widx * 4];
            f32x4 a1 = *(const f32x4*)&CI1[widx * 4];
            if (t > 0) {
                while (__hip_atomic_load(bar, __ATOMIC_ACQUIRE,
                                         __HIP_MEMORY_SCOPE_AGENT) < NWG * t)
                    __builtin_amdgcn_s_sleep(1);
                // deferred exit flag: chg[t-1] is final once bar >= 8t
                if (tid == 0)
                    sexit = __hip_atomic_load(&chg[t - 1], __ATOMIC_RELAXED,
                                              __HIP_MEMORY_SCOPE_AGENT);
                const uint4* hgr = (const uint4*)(((t - 1) & 1) ? hg1 : hg0);
                uint4 u[8];
                #pragma unroll
                for (int kc = 0; kc < 8; ++kc)  // 8 dense 16-B coherent loads
                    u[kc] = ldg_coherent(hgr + kc * 64 + l15 * 4 + quad);
                asm volatile("s_waitcnt vmcnt(0)" ::: "memory");
                __builtin_amdgcn_sched_barrier(0);  // rule #18: pin MFMA after fence
                #pragma unroll
                for (int kc = 0; kc < 8; ++kc) {
                    bf16x8 av = __builtin_bit_cast(bf16x8, u[kc]);
                    a0 = __builtin_amdgcn_mfma_f32_16x16x32_bf16(av, B0[kc], a0, 0, 0, 0);
                    a1 = __builtin_amdgcn_mfma_f32_16x16x32_bf16(av, B1[kc], a1, 0, 0, 0);
                }
            }
            *(f32x4*)&X[((w * 2 + 0) * 256 + lane) * 4] = a0;
            *(f32x4*)&X[((w * 2 + 1) * 256 + lane) * 4] = a1;
        }
        __syncthreads();                                // S1: X ready
        if (t > 0 && sexit == 0) { S = t - 1; break; }  // unanimous (final value)

        // ---- epilogue: combine gates for elements (erow, ec) and (erow, ec+1) ----
        float hv0, hv1;
        bool mv = false;
        {
            const int c0 = ec, c1 = ec + 1;
            const int xb0 = ((c0 >> 4) * 256 + (erow >> 2) * 16 + (c0 & 15)) * 4 + (erow & 3);
            float r = sigm_h(X[xb0]);
            float z = sigm_h(X[xb0 + 2048]);
            float n = tanh7(fmaf(r, X[xb0 + 4096], gnl[erow][c0]));
            hv0 = fmaf(z, hp0 - n, n);
            mv |= fabsf(hv0 - hp0) > 1e-4f;
            hp0 = hv0;
            const int xb1 = ((c1 >> 4) * 256 + (erow >> 2) * 16 + (c1 & 15)) * 4 + (erow & 3);
            r = sigm_h(X[xb1]);
            z = sigm_h(X[xb1 + 2048]);
            n = tanh7(fmaf(r, X[xb1 + 4096], gnl[erow][c1]));
            hv1 = fmaf(z, hp1 - n, n);
            mv |= fabsf(hv1 - hp1) > 1e-4f;
            hp1 = hv1;
        }
        // out row t (f32, full precision)
        *(float2*)&out[(size_t)erow * 65536 + (size_t)t * 256 + cb + ec] = make_float2(hv0, hv1);
        // publish h slice, chunk-tiled: u32 slot wg*256 + tid (coalesced 1 KB)
        {
            unsigned p = ((unsigned)__builtin_bit_cast(unsigned short, (__bf16)hv1) << 16)
                       |  (unsigned)__builtin_bit_cast(unsigned short, (__bf16)hv0);
            unsigned* hgw = (t & 1) ? hg1 : hg0;
            __hip_atomic_store(&hgw[wg * 256 + tid], p,
                               __ATOMIC_RELAXED, __HIP_MEMORY_SCOPE_AGENT);
        }
        if (lane == 0) wchg[w] = __any(mv) ? 1 : 0;
        __syncthreads();      // S2: drain publishes (vmcnt0) + wchg visible
        if (tid == 0) {       // chg-OR BEFORE release-add: ordered by release
            if (wchg[0] | wchg[1] | wchg[2] | wchg[3])
                __hip_atomic_fetch_or(&chg[t], 1, __ATOMIC_RELAXED, __HIP_MEMORY_SCOPE_AGENT);
            __hip_atomic_fetch_add(bar, 1, __ATOMIC_RELEASE, __HIP_MEMORY_SCOPE_AGENT);
        }
    }

    if (wg == 0 && tid == 0) meta[0] = S;
}

// ---------- kernel D: replicate row S into rows S+1..255 ----------
__global__ void fill_kernel(const int* __restrict__ meta, float* __restrict__ out) {
    const int S = meta[0];
    const int r = S + 1 + blockIdx.x;
    if (r > 255) return;
    const int c = threadIdx.x;
    #pragma unroll 4
    for (int b = 0; b < 16; ++b)
        out[b * 65536 + r * 256 + c] = out[b * 65536 + S * 256 + c];
}

extern "C" void kernel_launch(void* const* d_in, const int* in_sizes, int n_in,
                              void* d_out, int out_size, void* d_ws, size_t ws_size,
                              hipStream_t stream) {
    const float* x      = (const float*)d_in[0];
    const float* conv_w = (const float*)d_in[1];
    const float* conv_b = (const float*)d_in[2];
    const float* w_ih   = (const float*)d_in[3];
    const float* w_hh   = (const float*)d_in[4];
    const float* b_ih   = (const float*)d_in[5];
    const float* b_hh   = (const float*)d_in[6];
    float* out = (float*)d_out;

    float* ws    = (float*)d_ws;
    float* g     = ws;                         // 4096 floats
    float* maskb = ws + 4096;                  // 4096
    float* gib   = ws + 8192;                  // 12288
    int*   meta  = (int*)(ws + 20480);         // 1 int
    int*   bar   = (int*)(ws + 20512);         // own cacheline
    int*   chg   = (int*)(ws + 20544);         // 256 ints
    __bf16* wbf  = (__bf16*)(ws + 20816);      // 196608 bf16 (384 KB), 16B-aligned
    unsigned* hg0 = (unsigned*)(ws + 119120);  // 2048 u32 (8 KB), 16B-aligned
    unsigned* hg1 = (unsigned*)(ws + 121168);  // 2048 u32

    barinit_kernel<<<1, 256, 0, stream>>>(bar, chg);
    wcvt_kernel<<<192, 256, 0, stream>>>(w_hh, wbf);
    pool_kernel<<<BATCH * T, 256, 0, stream>>>(x, g);
    mask_kernel<<<T, 256, 0, stream>>>(g, conv_w, conv_b, maskb);
    gi_kernel<<<3 * T, 256, 0, stream>>>(maskb, w_ih, b_ih, gib);
    gru_kernel<<<NWG, 256, 0, stream>>>(gib, wbf, b_hh, out, meta, bar, chg, hg0, hg1);
    fill_kernel<<<T - 1, 256, 0, stream>>>(meta, out);
}

// Round 10
// 208.438 us; speedup vs baseline: 1.1985x; 1.0643x over previous
//
#include <hip/hip_runtime.h>
#include <hip/hip_bf16.h>

#define BATCH 16
#define T 256
#define DHW 5760  // 3*30*64
#define NWG 8     // GRU workgroups; WG i owns h-columns [32i, 32i+32) = K-chunk i

typedef __bf16 bf16x8 __attribute__((ext_vector_type(8)));
typedef __bf16 bf16x4 __attribute__((ext_vector_type(4)));
typedef float f32x4 __attribute__((ext_vector_type(4)));

// ---------- gate nonlinearities: odd Taylor, |arg| <~ 0.5 ----------
// sigm with PRE-HALVED argument u = x/2 (weights+gi for r,z are pre-scaled 0.5)
__device__ __forceinline__ float sigm_h(float u) {
    float t = u * u;
    float q = fmaf(t, fmaf(t, 1.0f / 15.0f, -1.0f / 6.0f), 0.5f);
    return fmaf(u, q, 0.5f);
}
__device__ __forceinline__ float tanh7(float x) {
    float t = x * x;
    float p = fmaf(t, fmaf(t, fmaf(t, -17.0f / 315.0f, 2.0f / 15.0f), -1.0f / 3.0f), 1.0f);
    return x * p;
}

// Cross-XCD coherent 16-B load: sc0 sc1 bypasses L1 + per-XCD L2 (reads the
// IF coherence point). Result regs NOT valid until a vmcnt fence AND a
// sched_barrier(0) (rule #18: reg-only consumers can be hoisted past waitcnt).
__device__ __forceinline__ uint4 ldg_coherent(const uint4* p) {
    uint4 r;
    asm volatile("global_load_dwordx4 %0, %1, off sc0 sc1" : "=v"(r) : "v"(p));
    return r;
}

// ---------- kernel W: w_hh f32 -> bf16, row-major [768][256]; block 0 zeroes seq ----------
__global__ void wcvt_kernel(const float* __restrict__ w_hh, __bf16* __restrict__ wbf,
                            int* __restrict__ seq) {
    if (blockIdx.x == 0 && threadIdx.x < 8)  // per-launch re-init, IF-visible store
        __hip_atomic_store(&seq[threadIdx.x], 0, __ATOMIC_RELAXED, __HIP_MEMORY_SCOPE_AGENT);
    const int idx = blockIdx.x * 256 + threadIdx.x;
    const float s = (idx < 32768) ? 0.5f : 1.0f;  // rows<512 (r,z) pre-halved
    const float4 v = ((const float4*)w_hh)[idx];
    bf16x4 o;
    o[0] = (__bf16)(v.x * s); o[1] = (__bf16)(v.y * s);
    o[2] = (__bf16)(v.z * s); o[3] = (__bf16)(v.w * s);
    *(bf16x4*)(wbf + (size_t)idx * 4) = o;
}

// ---------- kernel A: global average pool ----------
__global__ void pool_kernel(const float* __restrict__ x, float* __restrict__ g) {
    const int row = blockIdx.x;
    const float4* xr = (const float4*)(x + (size_t)row * DHW);
    float s = 0.0f;
    for (int i = threadIdx.x; i < DHW / 4; i += 256) {
        float4 v = xr[i];
        s += (v.x + v.y) + (v.z + v.w);
    }
    #pragma unroll
    for (int off = 32; off > 0; off >>= 1) s += __shfl_down(s, off, 64);
    __shared__ float red[4];
    const int lane = threadIdx.x & 63, wv = threadIdx.x >> 6;
    if (lane == 0) red[wv] = s;
    __syncthreads();
    if (threadIdx.x == 0) {
        float t = (red[0] + red[1]) + (red[2] + red[3]);
        g[row] = t * (1.0f / (float)DHW);
    }
}

// ---------- kernel B1 ----------
__global__ void mask_kernel(const float* __restrict__ g, const float* __restrict__ conv_w,
                            const float* __restrict__ conv_b, float* __restrict__ mask) {
    const int o = blockIdx.x, i = threadIdx.x;
    const int lane = i & 63, wv = i >> 6;
    const float wt = conv_w[o * 768 + 3 * i + 1];
    __shared__ float part[16][4];
    #pragma unroll 4
    for (int b = 0; b < 16; ++b) {
        float v = wt * g[b * 256 + i];
        #pragma unroll
        for (int off = 32; off > 0; off >>= 1) v += __shfl_down(v, off, 64);
        if (lane == 0) part[b][wv] = v;
    }
    __syncthreads();
    if (i < 16)
        mask[i * 256 + o] = part[i][0] + part[i][1] + part[i][2] + part[i][3] + conv_b[o];
}

// ---------- kernel B2 ----------
__global__ void gi_kernel(const float* __restrict__ mask, const float* __restrict__ w_ih,
                          const float* __restrict__ b_ih, float* __restrict__ gi) {
    const int j = blockIdx.x, o = threadIdx.x;
    const int lane = o & 63, wv = o >> 6;
    const float wt = w_ih[j * 256 + o];
    __shared__ float part[16][4];
    #pragma unroll 4
    for (int b = 0; b < 16; ++b) {
        float v = wt * mask[b * 256 + o];
        #pragma unroll
        for (int off = 32; off > 0; off >>= 1) v += __shfl_down(v, off, 64);
        if (lane == 0) part[b][wv] = v;
    }
    __syncthreads();
    if (o < 16) gi[o * 768 + j] = part[o][0] + part[o][1] + part[o][2] + part[o][3] + b_ih[j];
}

// ---------- kernel C: distributed GRU, 8 WGs x 256 thr ----------
// ROUND-10 (= round 9 + hazard fixes): keep round 8's proven structure
// (chunk-tiled exchange, deferred exit, 2 barriers/step); replace the CENTRAL
// bar counter (8 serialized RMWs to one IF line per step) with:
//  (a) per-WG seq slots: tid0 plain relaxed sc0sc1 store AFTER S2's implicit
//      vmcnt(0) drain (publishes already acked at IF when seq issues).
//      Consumers poll all 8 with 2 dwordx4 coherent loads, min >= t.
//      FIX vs r9: sched_barrier(0) after the spin's vmcnt(0) -- without it
//      the compiler may hoist the reg-only min/compare above the waitcnt
//      (rule #18) and exit the spin on stale registers.
//  (b) per-wave chg BYTES at chgb[t][wg][w], stored pre-S2 (drained by S2 =>
//      visible whenever seq is). Consumer ORs 32 bytes, loaded concurrently
//      with the A-loads under one vmcnt(0)+sched_barrier. No RMW; no
//      zero-init needed (all 32 bytes of step t-1 rewritten this run before
//      any consumer can read them).
// Buffer-reuse safety unchanged: spin at step t certifies all WGs completed
// step t-1 (incl. their hg[(t-2)&1] loads); no WG can lead by 2.
__global__ __launch_bounds__(256) void gru_kernel(
    const float* __restrict__ gi,    // [16][768]
    const __bf16* __restrict__ wbf,  // [768][256] bf16 (rows<512 pre-halved)
    const float* __restrict__ b_hh,  // [768]
    float* __restrict__ out,         // [16][256][256]
    int* __restrict__ meta,          // [0] = S
    int* __restrict__ seq,           // [8] per-WG completed-step counters
    unsigned char* __restrict__ chgb,// [256][8][4] per-step/WG/wave change bytes
    unsigned* __restrict__ hg0,      // h exchange buf A: chunk-tiled [8][256] u32
    unsigned* __restrict__ hg1)      // h exchange buf B
{
    __shared__ __align__(16) float X[6 * 256 * 4];      // 24576 B gate exchange
    __shared__ __align__(16) float CI0[768], CI1[768];  // gate-wave C-inits
    __shared__ float gnl[16][33];                       // gi_n slice
    __shared__ int sexit;

    const int tid = threadIdx.x;
    const int w = tid >> 6;          // wave 0..3 (0-2 compute gates r,z,n)
    const int lane = tid & 63;
    const int l15 = lane & 15;
    const int quad = lane >> 4;
    const int wg = blockIdx.x;
    const int cb = wg * 32;          // column base of this WG

    // ---- B-frags: wave w<3 owns gate w, col-tiles 0/1 -> 64 regs/wave ----
    bf16x8 B0[8], B1[8];
    if (w < 3) {
        const __bf16* wr0 = wbf + (size_t)(w * 256 + cb + l15) * 256 + quad * 8;
        const __bf16* wr1 = wr0 + 16 * 256;
        #pragma unroll
        for (int kc = 0; kc < 8; ++kc) {
            B0[kc] = *(const bf16x8*)(wr0 + kc * 32);
            B1[kc] = *(const bf16x8*)(wr1 + kc * 32);
            asm volatile("" : "+v"(B0[kc]), "+v"(B1[kc]));
        }
        // C-inits to LDS (register relief; re-read each step, 2 ds_read_b128)
        const int widx = w * 64 + lane;
        f32x4 c0, c1;
        if (w == 2) {  // n-gate C-init = b_hh_n broadcast (gi_n added in epilogue)
            const float bn0 = b_hh[512 + cb + l15];
            const float bn1 = b_hh[512 + cb + 16 + l15];
            c0[0] = bn0; c0[1] = bn0; c0[2] = bn0; c0[3] = bn0;
            c1[0] = bn1; c1[1] = bn1; c1[2] = bn1; c1[3] = bn1;
        } else {       // r/z C-init = 0.5*(gi + b_hh), rows = quad*4+i
            const int o0 = w * 256 + cb + l15;
            #pragma unroll
            for (int i = 0; i < 4; ++i) {
                c0[i] = (gi[(size_t)(quad * 4 + i) * 768 + o0] + b_hh[o0]) * 0.5f;
                c1[i] = (gi[(size_t)(quad * 4 + i) * 768 + o0 + 16] + b_hh[o0 + 16]) * 0.5f;
            }
        }
        *(f32x4*)&CI0[widx * 4] = c0;
        *(f32x4*)&CI1[widx * 4] = c1;
    }
    for (int e = tid; e < 512; e += 256)
        gnl[e >> 5][e & 31] = gi[(size_t)(e >> 5) * 768 + 512 + cb + (e & 31)];

    const int erow = tid >> 4;        // epilogue: batch row 0..15
    const int ec = (tid & 15) * 2;    // epilogue: local col pair
    float hp0 = 0.0f, hp1 = 0.0f;     // previous h for this thread's 2 elements
    int S = 255;
    __syncthreads();

    for (int t = 0; t < 256; ++t) {
        // ---- MFMA phase (gate waves): seq spin, A loads + chg loads, 16 MFMA ----
        if (w < 3) {
            const int widx = w * 64 + lane;
            f32x4 a0 = *(const f32x4*)&CI0[widx * 4];
            f32x4 a1 = *(const f32x4*)&CI1[widx * 4];
            if (t > 0) {
                // spin: all 8 per-WG seq slots >= t (two dense coherent loads)
                const uint4* sp = (const uint4*)seq;
                for (;;) {
                    uint4 s0 = ldg_coherent(sp);
                    uint4 s1 = ldg_coherent(sp + 1);
                    asm volatile("s_waitcnt vmcnt(0)" ::: "memory");
                    __builtin_amdgcn_sched_barrier(0);  // rule #18: no hoist past fence
                    int m0 = min(min((int)s0.x, (int)s0.y), min((int)s0.z, (int)s0.w));
                    int m1 = min(min((int)s1.x, (int)s1.y), min((int)s1.z, (int)s1.w));
                    if (min(m0, m1) >= t) break;
                    __builtin_amdgcn_s_sleep(1);
                }
                const uint4* hgr = (const uint4*)(((t - 1) & 1) ? hg1 : hg0);
                uint4 u[8];
                #pragma unroll
                for (int kc = 0; kc < 8; ++kc)  // 8 dense 16-B coherent loads
                    u[kc] = ldg_coherent(hgr + kc * 64 + l15 * 4 + quad);
                uint4 cA, cB;                    // exit bytes for step t-1 (tid0)
                if (tid == 0) {
                    cA = ldg_coherent((const uint4*)(chgb + (t - 1) * 32));
                    cB = ldg_coherent((const uint4*)(chgb + (t - 1) * 32 + 16));
                }
                asm volatile("s_waitcnt vmcnt(0)" ::: "memory");
                __builtin_amdgcn_sched_barrier(0);  // rule #18: pin MFMA after fence
                #pragma unroll
                for (int kc = 0; kc < 8; ++kc) {
                    bf16x8 av = __builtin_bit_cast(bf16x8, u[kc]);
                    a0 = __builtin_amdgcn_mfma_f32_16x16x32_bf16(av, B0[kc], a0, 0, 0, 0);
                    a1 = __builtin_amdgcn_mfma_f32_16x16x32_bf16(av, B1[kc], a1, 0, 0, 0);
                }
                if (tid == 0)
                    sexit = (int)(cA.x | cA.y | cA.z | cA.w | cB.x | cB.y | cB.z | cB.w);
            }
            *(f32x4*)&X[((w * 2 + 0) * 256 + lane) * 4] = a0;
            *(f32x4*)&X[((w * 2 + 1) * 256 + lane) * 4] = a1;
        }
        __syncthreads();                                // S1: X + sexit ready
        if (t > 0 && sexit == 0) { S = t - 1; break; }  // unanimous (final value)

        // ---- epilogue: combine gates for elements (erow, ec) and (erow, ec+1) ----
        float hv0, hv1;
        bool mv = false;
        {
            const int c0 = ec, c1 = ec + 1;
            const int xb0 = ((c0 >> 4) * 256 + (erow >> 2) * 16 + (c0 & 15)) * 4 + (erow & 3);
            float r = sigm_h(X[xb0]);
            float z = sigm_h(X[xb0 + 2048]);
            float n = tanh7(fmaf(r, X[xb0 + 4096], gnl[erow][c0]));
            hv0 = fmaf(z, hp0 - n, n);
            mv |= fabsf(hv0 - hp0) > 1e-4f;
            hp0 = hv0;
            const int xb1 = ((c1 >> 4) * 256 + (erow >> 2) * 16 + (c1 & 15)) * 4 + (erow & 3);
            r = sigm_h(X[xb1]);
            z = sigm_h(X[xb1 + 2048]);
            n = tanh7(fmaf(r, X[xb1 + 4096], gnl[erow][c1]));
            hv1 = fmaf(z, hp1 - n, n);
            mv |= fabsf(hv1 - hp1) > 1e-4f;
            hp1 = hv1;
        }
        // publish FIRST (acks overlap the rest), chunk-tiled: u32 slot wg*256+tid
        {
            unsigned p = ((unsigned)__builtin_bit_cast(unsigned short, (__bf16)hv1) << 16)
                       |  (unsigned)__builtin_bit_cast(unsigned short, (__bf16)hv0);
            unsigned* hgw = (t & 1) ? hg1 : hg0;
            __hip_atomic_store(&hgw[wg * 256 + tid], p,
                               __ATOMIC_RELAXED, __HIP_MEMORY_SCOPE_AGENT);
        }
        // out row t (f32, full precision)
        *(float2*)&out[(size_t)erow * 65536 + (size_t)t * 256 + cb + ec] = make_float2(hv0, hv1);
        // per-wave change byte, pre-S2 (drained by S2 => visible with seq)
        const bool wmv = __any(mv);
        if (lane == 0)
            __hip_atomic_store(chgb + t * 32 + wg * 4 + w, (unsigned char)(wmv ? 1 : 0),
                               __ATOMIC_RELAXED, __HIP_MEMORY_SCOPE_AGENT);
        __syncthreads();      // S2: drains publishes + chg bytes (vmcnt0/barrier)
        if (tid == 0)         // after drain => ordered; plain store, no RMW convoy
            __hip_atomic_store(&seq[wg], t + 1,
                               __ATOMIC_RELAXED, __HIP_MEMORY_SCOPE_AGENT);
    }

    if (wg == 0 && tid == 0) meta[0] = S;
}

// ---------- kernel D: replicate row S into rows S+1..255 ----------
__global__ void fill_kernel(const int* __restrict__ meta, float* __restrict__ out) {
    const int S = meta[0];
    const int r = S + 1 + blockIdx.x;
    if (r > 255) return;
    const int c = threadIdx.x;
    #pragma unroll 4
    for (int b = 0; b < 16; ++b)
        out[b * 65536 + r * 256 + c] = out[b * 65536 + S * 256 + c];
}

extern "C" void kernel_launch(void* const* d_in, const int* in_sizes, int n_in,
                              void* d_out, int out_size, void* d_ws, size_t ws_size,
                              hipStream_t stream) {
    const float* x      = (const float*)d_in[0];
    const float* conv_w = (const float*)d_in[1];
    const float* conv_b = (const float*)d_in[2];
    const float* w_ih   = (const float*)d_in[3];
    const float* w_hh   = (const float*)d_in[4];
    const float* b_ih   = (const float*)d_in[5];
    const float* b_hh   = (const float*)d_in[6];
    float* out = (float*)d_out;

    float* ws    = (float*)d_ws;
    float* g     = ws;                            // 4096 floats
    float* maskb = ws + 4096;                     // 4096
    float* gib   = ws + 8192;                     // 12288
    int*   meta  = (int*)(ws + 20480);            // 1 int
    int*   seqp  = (int*)(ws + 20488);            // 8 ints, 32B-aligned
    unsigned char* chgb = (unsigned char*)(ws + 20496);  // 256*32 B, 32B-aligned
    __bf16* wbf  = (__bf16*)(ws + 22544);         // 196608 bf16 (384 KB), 16B-aligned
    unsigned* hg0 = (unsigned*)(ws + 120848);     // 2048 u32 (8 KB), 16B-aligned
    unsigned* hg1 = (unsigned*)(ws + 122896);     // 2048 u32

    wcvt_kernel<<<192, 256, 0, stream>>>(w_hh, wbf, seqp);
    pool_kernel<<<BATCH * T, 256, 0, stream>>>(x, g);
    mask_kernel<<<T, 256, 0, stream>>>(g, conv_w, conv_b, maskb);
    gi_kernel<<<3 * T, 256, 0, stream>>>(maskb, w_ih, b_ih, gib);
    gru_kernel<<<NWG, 256, 0, stream>>>(gib, wbf, b_hh, out, meta, seqp, chgb, hg0, hg1);
    fill_kernel<<<T - 1, 256, 0, stream>>>(meta, out);
}